// Round 3
// baseline (215.213 us; speedup 1.0000x reference)
//
#include <hip/hip_runtime.h>
#include <hip/hip_bf16.h>

// out[b,0,f,t] = sum_{k=0}^{768} kernels[f,k] * x[b,0,t-k]  (zero-padded left).
// MFMA Toeplitz-GEMM, v_mfma_f32_32x32x16_bf16, diagonal B-fragment register ring.
// v2: pre-kernels convert to bf16 in d_ws (h k-reversed; x as 8 shifted copies),
// main kernel stages via vectorized b128 copies only. 1 block/CU, 16 waves.

#define BATCH 128
#define SEQ   8192
#define NF    20
#define KLEN  769

typedef short bf16x8 __attribute__((ext_vector_type(8)));
typedef float f32x16 __attribute__((ext_vector_type(16)));

static __device__ __forceinline__ unsigned short f2bf(float v) {
    __hip_bfloat16 h = __float2bfloat16(v);
    return *reinterpret_cast<unsigned short*>(&h);
}

// ---------------- pre-kernels (write bf16 into d_ws) ----------------
#define HSTRIDE_B 1616      // 808 bf16/row
#define XROW_B    18016     // 9008 bf16 per (b,rho) row
#define XBSTRIDE_B 144128   // 8 rows per batch
#define WS_X_OFF  65536
#define WS_REQ    (WS_X_OFF + (size_t)BATCH * XBSTRIDE_B)   // ~18.5 MB

// hv[f][p] = kernels[f][791-p] (k-reversed, zero outside [0,769) or f>=20)
__global__ void bpf_prep_h(const float* __restrict__ kg, char* __restrict__ hdst) {
    const int f = blockIdx.x;                 // 0..31
    for (int p = threadIdx.x; p < 808; p += blockDim.x) {
        int k = 791 - p;
        float v = (f < NF && k >= 0 && k < KLEN) ? kg[f * KLEN + k] : 0.0f;
        *reinterpret_cast<unsigned short*>(hdst + f * HSTRIDE_B + 2 * p) = f2bf(v);
    }
}

// xc[b][rho][q] = x[b][q - 800 + rho], q in [0,9008), zero-guarded
__global__ void bpf_prep_x(const float* __restrict__ xg, char* __restrict__ xdst) {
    const int y   = blockIdx.y;               // b*8 + rho
    const int b   = y >> 3;
    const int rho = y & 7;
    const int q0  = (blockIdx.x * blockDim.x + threadIdx.x) * 8;
    if (q0 >= 9008) return;
    const float* xb = xg + (size_t)b * SEQ;
    const int base = q0 - 800 + rho;
    bf16x8 v;
#pragma unroll
    for (int j = 0; j < 8; ++j) {
        int g = base + j;
        float f = (g >= 0 && g < SEQ) ? xb[g] : 0.0f;
        v[j] = (short)f2bf(f);
    }
    *reinterpret_cast<bf16x8*>(xdst + (size_t)y * XROW_B + 2 * q0) = v;
}

// ---------------- main kernel ----------------
#define V2_THREADS 1024
#define XS_LDS   9872                       // stride/16 = 617 (odd mod 8): conflict-opt
#define XREGION  (8 * XS_LDS)               // 78976
#define V2_LDSB  (XREGION + 32 * HSTRIDE_B) // 130688
#define KT       25

__global__ __launch_bounds__(V2_THREADS, 4)
void bpf_mfma_v2(const char* __restrict__ xsrc_all, const char* __restrict__ hsrc,
                 float* __restrict__ out) {
    extern __shared__ char smem[];
    char* xs = smem;
    char* hs = smem + XREGION;

    const int tid = threadIdx.x;
    const int b   = blockIdx.x >> 1;
    const int T0  = (blockIdx.x & 1) * 4096;

    // stage h: 51712 B = 3232 x 16B (bf16, pre-reversed)
    for (int v = tid; v < 3232; v += V2_THREADS) {
        *reinterpret_cast<bf16x8*>(hs + v * 16) =
            *reinterpret_cast<const bf16x8*>(hsrc + v * 16);
    }
    // stage x windows: 8 copies x 9824 B (614 x 16B each)
    {
        const char* xsrcb = xsrc_all + (size_t)b * XBSTRIDE_B + 2 * T0;
        if (tid < 614) {
#pragma unroll
            for (int rho = 0; rho < 8; ++rho) {
                *reinterpret_cast<bf16x8*>(xs + rho * XS_LDS + tid * 16) =
                    *reinterpret_cast<const bf16x8*>(xsrcb + rho * XROW_B + tid * 16);
            }
        }
    }
    __syncthreads();

    const int lane = tid & 63;
    const int wid  = tid >> 6;    // 0..15
    const int c    = lane & 31;   // A row (=f), B col (=t-offset), D col
    const int g2   = lane >> 5;

    const char* Abase = hs + c * HSTRIDE_B - 16 * g2;
    float* outb = out + (size_t)b * NF * SEQ;

    for (int ti = 0; ti < 2; ++ti) {
        const int n0     = T0 + (wid + 16 * ti) * 128;   // 128 t-cols per task
        const int s_base = n0 + c + 1 - 8 * g2 - 784;
        const int rho    = s_base & 7;
        const int ebase  = s_base - rho - (T0 - 800);
        const char* Bbase = xs + rho * XS_LDS + 2 * ebase;

        f32x16 acc[4];
#pragma unroll
        for (int wt = 0; wt < 4; ++wt)
#pragma unroll
            for (int r = 0; r < 16; ++r) acc[wt][r] = 0.0f;

        bf16x8 ring[4][2];
#pragma unroll
        for (int wt = 0; wt < 4; ++wt) {
            ring[(4 - wt) & 3][0] = *reinterpret_cast<const bf16x8*>(Bbase + 1568 + 64 * wt);
            ring[(4 - wt) & 3][1] = *reinterpret_cast<const bf16x8*>(Bbase + 1536 + 64 * wt);
        }

#pragma unroll
        for (int i = 0; i < KT; ++i) {
            bf16x8 na, nb;
            if (i < KT - 1) {   // prefetch pair(i+1, 0)
                na = *reinterpret_cast<const bf16x8*>(Bbase + 64 * (23 - i) + 32);
                nb = *reinterpret_cast<const bf16x8*>(Bbase + 64 * (23 - i));
            }
            bf16x8 a0 = *reinterpret_cast<const bf16x8*>(Abase + 1584 - 64 * i);
            bf16x8 a1 = *reinterpret_cast<const bf16x8*>(Abase + 1552 - 64 * i);
#pragma unroll
            for (int wt = 0; wt < 4; ++wt)
                acc[wt] = __builtin_amdgcn_mfma_f32_32x32x16_bf16(
                    a0, ring[(i - wt) & 3][0], acc[wt], 0, 0, 0);
#pragma unroll
            for (int wt = 0; wt < 4; ++wt)
                acc[wt] = __builtin_amdgcn_mfma_f32_32x32x16_bf16(
                    a1, ring[(i - wt) & 3][1], acc[wt], 0, 0, 0);
            if (i < KT - 1) {
                ring[(i + 1) & 3][0] = na;
                ring[(i + 1) & 3][1] = nb;
            }
        }

        // D: col = lane&31 (t), row f = (r&3) + 8*(r>>2) + 4*g2
#pragma unroll
        for (int wt = 0; wt < 4; ++wt) {
            const int tcol = n0 + 32 * wt + c;
#pragma unroll
            for (int r = 0; r < 16; ++r) {
                const int f = (r & 3) + 8 * (r >> 2) + 4 * g2;
                if (f < NF) outb[f * SEQ + tcol] = acc[wt][r];
            }
        }
    }
}

// ---------------- fallback (verified round-2 kernel, self-staging) ----------------
#define FB_THREADS 512
#define FB_XSTRIDE 5776
#define FB_XN      2864
#define FB_XBYTES  (8 * FB_XSTRIDE)
#define FB_LDSB    (FB_XBYTES + 32 * HSTRIDE_B)   // 97920

__global__ __launch_bounds__(FB_THREADS, 2)
void bpf_mfma_fb(const float* __restrict__ xg, const float* __restrict__ kg,
                 float* __restrict__ out) {
    extern __shared__ char smem[];
    char* xs = smem;
    char* hs = smem + FB_XBYTES;

    const int tid = threadIdx.x;
    const int b   = blockIdx.x >> 2;
    const int T0  = (blockIdx.x & 3) * 2048;
    const int E0  = T0 - 800;

    for (int idx = tid; idx < 32 * 800; idx += FB_THREADS) {
        int f = idx / 800;
        int p = idx - f * 800;
        int k = 791 - p;
        float v = 0.0f;
        if (f < NF && k >= 0 && k < KLEN) v = kg[f * KLEN + k];
        *reinterpret_cast<unsigned short*>(hs + f * HSTRIDE_B + 2 * p) = f2bf(v);
    }
    const float* xb = xg + (size_t)b * SEQ;
    for (int rho = 0; rho < 8; ++rho) {
        char* xr = xs + rho * FB_XSTRIDE;
        for (int e = tid; e < FB_XN; e += FB_THREADS) {
            int g = E0 + rho + e;
            float v = (g >= 0 && g < SEQ) ? xb[g] : 0.0f;
            *reinterpret_cast<unsigned short*>(xr + 2 * e) = f2bf(v);
        }
    }
    __syncthreads();

    const int lane = tid & 63;
    const int wid  = tid >> 6;
    const int c    = lane & 31;
    const int g2   = lane >> 5;
    const char* Abase = hs + c * HSTRIDE_B - 16 * g2;
    float* outb = out + (size_t)b * NF * SEQ;

    for (int ti = 0; ti < 2; ++ti) {
        const int n0     = T0 + (wid + 8 * ti) * 128;
        const int s_base = n0 + c + 1 - 8 * g2 - 784;
        const int rho    = s_base & 7;
        const int ebase  = s_base - rho - E0;
        const char* Bbase = xs + rho * FB_XSTRIDE + 2 * ebase;

        f32x16 acc[4];
#pragma unroll
        for (int wt = 0; wt < 4; ++wt)
#pragma unroll
            for (int r = 0; r < 16; ++r) acc[wt][r] = 0.0f;

        bf16x8 ring[4][2];
#pragma unroll
        for (int wt = 0; wt < 4; ++wt) {
            ring[(4 - wt) & 3][0] = *reinterpret_cast<const bf16x8*>(Bbase + 1568 + 64 * wt);
            ring[(4 - wt) & 3][1] = *reinterpret_cast<const bf16x8*>(Bbase + 1536 + 64 * wt);
        }
#pragma unroll
        for (int i = 0; i < KT; ++i) {
            bf16x8 na, nb;
            if (i < KT - 1) {
                na = *reinterpret_cast<const bf16x8*>(Bbase + 64 * (23 - i) + 32);
                nb = *reinterpret_cast<const bf16x8*>(Bbase + 64 * (23 - i));
            }
            bf16x8 a0 = *reinterpret_cast<const bf16x8*>(Abase + 1584 - 64 * i);
            bf16x8 a1 = *reinterpret_cast<const bf16x8*>(Abase + 1552 - 64 * i);
#pragma unroll
            for (int wt = 0; wt < 4; ++wt)
                acc[wt] = __builtin_amdgcn_mfma_f32_32x32x16_bf16(
                    a0, ring[(i - wt) & 3][0], acc[wt], 0, 0, 0);
#pragma unroll
            for (int wt = 0; wt < 4; ++wt)
                acc[wt] = __builtin_amdgcn_mfma_f32_32x32x16_bf16(
                    a1, ring[(i - wt) & 3][1], acc[wt], 0, 0, 0);
            if (i < KT - 1) {
                ring[(i + 1) & 3][0] = na;
                ring[(i + 1) & 3][1] = nb;
            }
        }
#pragma unroll
        for (int wt = 0; wt < 4; ++wt) {
            const int tcol = n0 + 32 * wt + c;
#pragma unroll
            for (int r = 0; r < 16; ++r) {
                const int f = (r & 3) + 8 * (r >> 2) + 4 * g2;
                if (f < NF) outb[f * SEQ + tcol] = acc[wt][r];
            }
        }
    }
}

extern "C" void kernel_launch(void* const* d_in, const int* in_sizes, int n_in,
                              void* d_out, int out_size, void* d_ws, size_t ws_size,
                              hipStream_t stream) {
    const float* x    = (const float*)d_in[0];   // (128,1,8192) f32
    const float* kern = (const float*)d_in[1];   // (20,769)     f32
    float* out = (float*)d_out;                  // (128,1,20,8192) f32
    (void)in_sizes; (void)n_in; (void)out_size;

    if (ws_size >= WS_REQ) {
        char* ws = (char*)d_ws;
        bpf_prep_h<<<32, 256, 0, stream>>>(kern, ws);
        bpf_prep_x<<<dim3(5, BATCH * 8), 256, 0, stream>>>(x, ws + WS_X_OFF);
        hipFuncSetAttribute(reinterpret_cast<const void*>(bpf_mfma_v2),
                            hipFuncAttributeMaxDynamicSharedMemorySize, V2_LDSB);
        bpf_mfma_v2<<<BATCH * 2, V2_THREADS, V2_LDSB, stream>>>(ws + WS_X_OFF, ws, out);
    } else {
        hipFuncSetAttribute(reinterpret_cast<const void*>(bpf_mfma_fb),
                            hipFuncAttributeMaxDynamicSharedMemorySize, FB_LDSB);
        bpf_mfma_fb<<<BATCH * 4, FB_THREADS, FB_LDSB, stream>>>(x, kern, out);
    }
}

// Round 4
// 212.070 us; speedup vs baseline: 1.0148x; 1.0148x over previous
//
#include <hip/hip_runtime.h>
#include <hip/hip_bf16.h>

// out[b,0,f,t] = sum_{k=0}^{768} kernels[f,k] * x[b,0,t-k]  (zero-padded left).
// MFMA Toeplitz-GEMM, v_mfma_f32_32x32x16_bf16, diagonal B-fragment register ring.
// v3: prep kernels convert to bf16 in d_ws; main kernel = round-2-proven inner
// loop, 512 thr, 20-row h in LDS (78.5 KB total) -> 2 blocks/CU, 4 waves/SIMD.

#define BATCH 128
#define SEQ   8192
#define NF    20
#define KLEN  769
#define KT    25

typedef short bf16x8 __attribute__((ext_vector_type(8)));
typedef float f32x16 __attribute__((ext_vector_type(16)));

static __device__ __forceinline__ unsigned short f2bf(float v) {
    __hip_bfloat16 h = __float2bfloat16(v);
    return *reinterpret_cast<unsigned short*>(&h);
}

// ---------------- workspace layout ----------------
#define HSTRIDE_B 1616      // 808 bf16/row; mod 128 = 80 = 16*5 (conflict-optimal)
#define XROW_B    18016     // 9008 bf16 per (b,rho) row
#define XBSTRIDE_B 144128   // 8 rho-rows per batch
#define WS_X_OFF  65536
#define WS_REQ    (WS_X_OFF + (size_t)BATCH * XBSTRIDE_B)   // ~18.5 MB

// hv[f][p] = kernels[f][791-p] (k-reversed; zero outside [0,769) or f>=20)
__global__ void bpf_prep_h(const float* __restrict__ kg, char* __restrict__ hdst) {
    const int f = blockIdx.x;                 // 0..31
    for (int p = threadIdx.x; p < 808; p += blockDim.x) {
        int k = 791 - p;
        float v = (f < NF && k >= 0 && k < KLEN) ? kg[f * KLEN + k] : 0.0f;
        *reinterpret_cast<unsigned short*>(hdst + f * HSTRIDE_B + 2 * p) = f2bf(v);
    }
}

// xc[b][rho][q] = x[b][q - 800 + rho], q in [0,9008), zero-guarded
__global__ void bpf_prep_x(const float* __restrict__ xg, char* __restrict__ xdst) {
    const int y   = blockIdx.y;               // b*8 + rho
    const int b   = y >> 3;
    const int rho = y & 7;
    const int q0  = (blockIdx.x * blockDim.x + threadIdx.x) * 8;
    if (q0 >= 9008) return;
    const float* xb = xg + (size_t)b * SEQ;
    const int base = q0 - 800 + rho;
    bf16x8 v;
#pragma unroll
    for (int j = 0; j < 8; ++j) {
        int g = base + j;
        float f = (g >= 0 && g < SEQ) ? xb[g] : 0.0f;
        v[j] = (short)f2bf(f);
    }
    *reinterpret_cast<bf16x8*>(xdst + (size_t)y * XROW_B + 2 * q0) = v;
}

// ---------------- main kernel ----------------
#define V3_THREADS 512
#define V3_XS     5776                        // LDS copy stride; mod 128 = 16
#define V3_XREG   (8 * V3_XS)                 // 46208
#define V3_HREG   (NF * HSTRIDE_B)            // 32320 (20 rows only)
#define V3_LDSB   (V3_XREG + V3_HREG)         // 78528 -> 2 blocks/CU

__global__ __launch_bounds__(V3_THREADS, 4)
void bpf_mfma_v3(const char* __restrict__ xsrc_all, const char* __restrict__ hsrc,
                 float* __restrict__ out) {
    extern __shared__ char smem[];
    char* xs = smem;
    char* hs = smem + V3_XREG;

    const int tid = threadIdx.x;
    const int b   = blockIdx.x >> 2;
    const int T0  = (blockIdx.x & 2048 / 2048 * 3) * 2048;   // (blockIdx.x & 3) * 2048
    const int E0  = T0 - 800;

    // stage h rows 0..19: contiguous 32320 B = 2020 x 16B
    for (int v = tid; v < 2020; v += V3_THREADS) {
        *reinterpret_cast<bf16x8*>(hs + v * 16) =
            *reinterpret_cast<const bf16x8*>(hsrc + v * 16);
    }
    // stage x: 8 copies x 5712 B (357 x 16B each) from pre-shifted WS rows
    {
        const char* xsrcb = xsrc_all + (size_t)b * XBSTRIDE_B + 2 * T0;
        for (int v = tid; v < 8 * 357; v += V3_THREADS) {
            int rho = v / 357;
            int j   = v - rho * 357;
            *reinterpret_cast<bf16x8*>(xs + rho * V3_XS + j * 16) =
                *reinterpret_cast<const bf16x8*>(xsrcb + rho * XROW_B + j * 16);
        }
    }
    __syncthreads();

    const int lane = tid & 63;
    const int wid  = tid >> 6;    // 0..7
    const int c    = lane & 31;   // A row (=f), B col (=t-offset), D col
    const int g2   = lane >> 5;

    // lanes c>=20 read h row 0 (their D rows are discarded; A row m only feeds D row m)
    const int hrow = (c < NF) ? c : 0;
    const char* Abase = hs + hrow * HSTRIDE_B - 16 * g2;
    float* outb = out + (size_t)b * NF * SEQ;

    for (int ti = 0; ti < 2; ++ti) {
        const int n0     = T0 + (wid + 8 * ti) * 128;   // 128 t-cols per task
        const int s_base = n0 + c + 1 - 8 * g2 - 784;
        const int rho    = s_base & 7;
        const int ebase  = s_base - rho - E0;           // >= 2, == 0 mod 8
        const char* Bbase = xs + rho * V3_XS + 2 * ebase;

        f32x16 acc[4];
#pragma unroll
        for (int wt = 0; wt < 4; ++wt)
#pragma unroll
            for (int r = 0; r < 16; ++r) acc[wt][r] = 0.0f;

        bf16x8 ring[4][2];
#pragma unroll
        for (int wt = 0; wt < 4; ++wt) {
            ring[(4 - wt) & 3][0] = *reinterpret_cast<const bf16x8*>(Bbase + 1568 + 64 * wt);
            ring[(4 - wt) & 3][1] = *reinterpret_cast<const bf16x8*>(Bbase + 1536 + 64 * wt);
        }

#pragma unroll
        for (int i = 0; i < KT; ++i) {
            bf16x8 na, nb;
            if (i < KT - 1) {   // prefetch pair(i+1, 0)
                na = *reinterpret_cast<const bf16x8*>(Bbase + 64 * (23 - i) + 32);
                nb = *reinterpret_cast<const bf16x8*>(Bbase + 64 * (23 - i));
            }
            bf16x8 a0 = *reinterpret_cast<const bf16x8*>(Abase + 1584 - 64 * i);
            bf16x8 a1 = *reinterpret_cast<const bf16x8*>(Abase + 1552 - 64 * i);
#pragma unroll
            for (int wt = 0; wt < 4; ++wt)
                acc[wt] = __builtin_amdgcn_mfma_f32_32x32x16_bf16(
                    a0, ring[(i - wt) & 3][0], acc[wt], 0, 0, 0);
#pragma unroll
            for (int wt = 0; wt < 4; ++wt)
                acc[wt] = __builtin_amdgcn_mfma_f32_32x32x16_bf16(
                    a1, ring[(i - wt) & 3][1], acc[wt], 0, 0, 0);
            if (i < KT - 1) {
                ring[(i + 1) & 3][0] = na;
                ring[(i + 1) & 3][1] = nb;
            }
        }

        // D: col = lane&31 (t), row f = (r&3) + 8*(r>>2) + 4*g2
#pragma unroll
        for (int wt = 0; wt < 4; ++wt) {
            const int tcol = n0 + 32 * wt + c;
#pragma unroll
            for (int r = 0; r < 16; ++r) {
                const int f = (r & 3) + 8 * (r >> 2) + 4 * g2;
                if (f < NF) outb[f * SEQ + tcol] = acc[wt][r];
            }
        }
    }
}

// ---------------- fallback (verified round-2 kernel, self-staging) ----------------
#define FB_THREADS 512
#define FB_XSTRIDE 5776
#define FB_XN      2864
#define FB_XBYTES  (8 * FB_XSTRIDE)
#define FB_LDSB    (FB_XBYTES + 32 * HSTRIDE_B)   // 97920

__global__ __launch_bounds__(FB_THREADS, 2)
void bpf_mfma_fb(const float* __restrict__ xg, const float* __restrict__ kg,
                 float* __restrict__ out) {
    extern __shared__ char smem[];
    char* xs = smem;
    char* hs = smem + FB_XBYTES;

    const int tid = threadIdx.x;
    const int b   = blockIdx.x >> 2;
    const int T0  = (blockIdx.x & 3) * 2048;
    const int E0  = T0 - 800;

    for (int idx = tid; idx < 32 * 800; idx += FB_THREADS) {
        int f = idx / 800;
        int p = idx - f * 800;
        int k = 791 - p;
        float v = 0.0f;
        if (f < NF && k >= 0 && k < KLEN) v = kg[f * KLEN + k];
        *reinterpret_cast<unsigned short*>(hs + f * HSTRIDE_B + 2 * p) = f2bf(v);
    }
    const float* xb = xg + (size_t)b * SEQ;
    for (int rho = 0; rho < 8; ++rho) {
        char* xr = xs + rho * FB_XSTRIDE;
        for (int e = tid; e < FB_XN; e += FB_THREADS) {
            int g = E0 + rho + e;
            float v = (g >= 0 && g < SEQ) ? xb[g] : 0.0f;
            *reinterpret_cast<unsigned short*>(xr + 2 * e) = f2bf(v);
        }
    }
    __syncthreads();

    const int lane = tid & 63;
    const int wid  = tid >> 6;
    const int c    = lane & 31;
    const int g2   = lane >> 5;
    const char* Abase = hs + c * HSTRIDE_B - 16 * g2;
    float* outb = out + (size_t)b * NF * SEQ;

    for (int ti = 0; ti < 2; ++ti) {
        const int n0     = T0 + (wid + 8 * ti) * 128;
        const int s_base = n0 + c + 1 - 8 * g2 - 784;
        const int rho    = s_base & 7;
        const int ebase  = s_base - rho - E0;
        const char* Bbase = xs + rho * FB_XSTRIDE + 2 * ebase;

        f32x16 acc[4];
#pragma unroll
        for (int wt = 0; wt < 4; ++wt)
#pragma unroll
            for (int r = 0; r < 16; ++r) acc[wt][r] = 0.0f;

        bf16x8 ring[4][2];
#pragma unroll
        for (int wt = 0; wt < 4; ++wt) {
            ring[(4 - wt) & 3][0] = *reinterpret_cast<const bf16x8*>(Bbase + 1568 + 64 * wt);
            ring[(4 - wt) & 3][1] = *reinterpret_cast<const bf16x8*>(Bbase + 1536 + 64 * wt);
        }
#pragma unroll
        for (int i = 0; i < KT; ++i) {
            bf16x8 na, nb;
            if (i < KT - 1) {
                na = *reinterpret_cast<const bf16x8*>(Bbase + 64 * (23 - i) + 32);
                nb = *reinterpret_cast<const bf16x8*>(Bbase + 64 * (23 - i));
            }
            bf16x8 a0 = *reinterpret_cast<const bf16x8*>(Abase + 1584 - 64 * i);
            bf16x8 a1 = *reinterpret_cast<const bf16x8*>(Abase + 1552 - 64 * i);
#pragma unroll
            for (int wt = 0; wt < 4; ++wt)
                acc[wt] = __builtin_amdgcn_mfma_f32_32x32x16_bf16(
                    a0, ring[(i - wt) & 3][0], acc[wt], 0, 0, 0);
#pragma unroll
            for (int wt = 0; wt < 4; ++wt)
                acc[wt] = __builtin_amdgcn_mfma_f32_32x32x16_bf16(
                    a1, ring[(i - wt) & 3][1], acc[wt], 0, 0, 0);
            if (i < KT - 1) {
                ring[(i + 1) & 3][0] = na;
                ring[(i + 1) & 3][1] = nb;
            }
        }
#pragma unroll
        for (int wt = 0; wt < 4; ++wt) {
            const int tcol = n0 + 32 * wt + c;
#pragma unroll
            for (int r = 0; r < 16; ++r) {
                const int f = (r & 3) + 8 * (r >> 2) + 4 * g2;
                if (f < NF) outb[f * SEQ + tcol] = acc[wt][r];
            }
        }
    }
}

extern "C" void kernel_launch(void* const* d_in, const int* in_sizes, int n_in,
                              void* d_out, int out_size, void* d_ws, size_t ws_size,
                              hipStream_t stream) {
    const float* x    = (const float*)d_in[0];   // (128,1,8192) f32
    const float* kern = (const float*)d_in[1];   // (20,769)     f32
    float* out = (float*)d_out;                  // (128,1,20,8192) f32
    (void)in_sizes; (void)n_in; (void)out_size;

    if (ws_size >= WS_REQ) {
        char* ws = (char*)d_ws;
        bpf_prep_h<<<32, 256, 0, stream>>>(kern, ws);
        bpf_prep_x<<<dim3(5, BATCH * 8), 256, 0, stream>>>(x, ws + WS_X_OFF);
        hipFuncSetAttribute(reinterpret_cast<const void*>(bpf_mfma_v3),
                            hipFuncAttributeMaxDynamicSharedMemorySize, V3_LDSB);
        bpf_mfma_v3<<<BATCH * 4, V3_THREADS, V3_LDSB, stream>>>(ws + WS_X_OFF, ws, out);
    } else {
        hipFuncSetAttribute(reinterpret_cast<const void*>(bpf_mfma_fb),
                            hipFuncAttributeMaxDynamicSharedMemorySize, FB_LDSB);
        bpf_mfma_fb<<<BATCH * 4, FB_THREADS, FB_LDSB, stream>>>(x, kern, out);
    }
}

// Round 5
// 204.102 us; speedup vs baseline: 1.0544x; 1.0390x over previous
//
#include <hip/hip_runtime.h>
#include <hip/hip_bf16.h>

// out[b,0,f,t] = sum_{k=0}^{768} kernels[f,k] * x[b,0,t-k]  (zero-padded left).
// MFMA Toeplitz-GEMM, v_mfma_f32_32x32x16_bf16, diagonal B-fragment register ring.
// v5: prep kernels convert to bf16 in d_ws; main kernel fits 64 VGPR + 64 AGPR
// (ring double-buffer temps removed) so __launch_bounds__(512,4) holds WITHOUT
// spill: 2 blocks/CU x 8 waves = 16 waves/CU, LDS 78.5 KB/block.

#define BATCH 128
#define SEQ   8192
#define NF    20
#define KLEN  769
#define KT    25

typedef short bf16x8 __attribute__((ext_vector_type(8)));
typedef float f32x16 __attribute__((ext_vector_type(16)));

static __device__ __forceinline__ unsigned short f2bf(float v) {
    __hip_bfloat16 h = __float2bfloat16(v);
    return *reinterpret_cast<unsigned short*>(&h);
}

// ---------------- workspace layout ----------------
#define HSTRIDE_B 1616      // 808 bf16/row; mod 128 = 80 (conflict-optimal)
#define XROW_B    18016     // 9008 bf16 per (b,rho) row
#define XBSTRIDE_B 144128   // 8 rho-rows per batch
#define WS_X_OFF  65536
#define WS_REQ    (WS_X_OFF + (size_t)BATCH * XBSTRIDE_B)   // ~18.5 MB

// hv[f][p] = kernels[f][791-p] (k-reversed; zero outside [0,769) or f>=20)
__global__ void bpf_prep_h(const float* __restrict__ kg, char* __restrict__ hdst) {
    const int f = blockIdx.x;                 // 0..31
    for (int p = threadIdx.x; p < 808; p += blockDim.x) {
        int k = 791 - p;
        float v = (f < NF && k >= 0 && k < KLEN) ? kg[f * KLEN + k] : 0.0f;
        *reinterpret_cast<unsigned short*>(hdst + f * HSTRIDE_B + 2 * p) = f2bf(v);
    }
}

// xc[b][rho][q] = x[b][q - 800 + rho], q in [0,9008), zero-guarded
__global__ void bpf_prep_x(const float* __restrict__ xg, char* __restrict__ xdst) {
    const int y   = blockIdx.y;               // b*8 + rho
    const int b   = y >> 3;
    const int rho = y & 7;
    const int q0  = (blockIdx.x * blockDim.x + threadIdx.x) * 8;
    if (q0 >= 9008) return;
    const float* xb = xg + (size_t)b * SEQ;
    const int base = q0 - 800 + rho;
    bf16x8 v;
#pragma unroll
    for (int j = 0; j < 8; ++j) {
        int g = base + j;
        float f = (g >= 0 && g < SEQ) ? xb[g] : 0.0f;
        v[j] = (short)f2bf(f);
    }
    *reinterpret_cast<bf16x8*>(xdst + (size_t)y * XROW_B + 2 * q0) = v;
}

// ---------------- main kernel ----------------
#define V5_THREADS 512
#define V5_XS     5776                        // LDS copy stride; mod 128 = 16
#define V5_XREG   (8 * V5_XS)                 // 46208
#define V5_HREG   (NF * HSTRIDE_B)            // 32320 (20 rows only)
#define V5_LDSB   (V5_XREG + V5_HREG)         // 78528 -> 2 blocks/CU

__global__ __launch_bounds__(V5_THREADS, 4)
void bpf_mfma_v5(const char* __restrict__ xsrc_all, const char* __restrict__ hsrc,
                 float* __restrict__ out) {
    extern __shared__ char smem[];
    char* xs = smem;
    char* hs = smem + V5_XREG;

    const int tid = threadIdx.x;
    const int b   = blockIdx.x >> 2;
    const int T0  = (blockIdx.x & 3) * 2048;
    const int E0  = T0 - 800;

    // stage h rows 0..19: contiguous 32320 B = 2020 x 16B (bf16, pre-reversed)
    for (int v = tid; v < 2020; v += V5_THREADS) {
        *reinterpret_cast<bf16x8*>(hs + v * 16) =
            *reinterpret_cast<const bf16x8*>(hsrc + v * 16);
    }
    // stage x: 8 copies x 5712 B (357 x 16B each) from pre-shifted WS rows
    {
        const char* xsrcb = xsrc_all + (size_t)b * XBSTRIDE_B + 2 * T0;
        for (int v = tid; v < 8 * 357; v += V5_THREADS) {
            int rho = v / 357;
            int j   = v - rho * 357;
            *reinterpret_cast<bf16x8*>(xs + rho * V5_XS + j * 16) =
                *reinterpret_cast<const bf16x8*>(xsrcb + rho * XROW_B + j * 16);
        }
    }
    __syncthreads();

    const int lane = tid & 63;
    const int wid  = tid >> 6;    // 0..7
    const int c    = lane & 31;   // A row (=f), B col (=t-offset), D col
    const int g2   = lane >> 5;

    // lanes c>=20 read h row 0 (their D rows are discarded; A row m only feeds D row m)
    const int hrow = (c < NF) ? c : 0;
    const char* Abase = hs + hrow * HSTRIDE_B - 16 * g2;
    float* outb = out + (size_t)b * NF * SEQ;

    for (int ti = 0; ti < 2; ++ti) {
        const int n0     = T0 + (wid + 8 * ti) * 128;   // 128 t-cols per task
        const int s_base = n0 + c + 1 - 8 * g2 - 784;
        const int rho    = s_base & 7;
        const int ebase  = s_base - rho - E0;           // >= 2, == 0 mod 8
        const char* Bbase = xs + rho * V5_XS + 2 * ebase;

        f32x16 acc[4];
#pragma unroll
        for (int wt = 0; wt < 4; ++wt)
#pragma unroll
            for (int r = 0; r < 16; ++r) acc[wt][r] = 0.0f;

        // prologue: pair(0,wt) -> ring[(4-wt)&3]
        bf16x8 ring[4][2];
#pragma unroll
        for (int wt = 0; wt < 4; ++wt) {
            ring[(4 - wt) & 3][0] = *reinterpret_cast<const bf16x8*>(Bbase + 1568 + 64 * wt);
            ring[(4 - wt) & 3][1] = *reinterpret_cast<const bf16x8*>(Bbase + 1536 + 64 * wt);
        }

#pragma unroll
        for (int i = 0; i < KT; ++i) {
            bf16x8 a0 = *reinterpret_cast<const bf16x8*>(Abase + 1584 - 64 * i);
            bf16x8 a1 = *reinterpret_cast<const bf16x8*>(Abase + 1552 - 64 * i);
#pragma unroll
            for (int wt = 0; wt < 4; ++wt)
                acc[wt] = __builtin_amdgcn_mfma_f32_32x32x16_bf16(
                    a0, ring[(i - wt) & 3][0], acc[wt], 0, 0, 0);
#pragma unroll
            for (int wt = 0; wt < 4; ++wt)
                acc[wt] = __builtin_amdgcn_mfma_f32_32x32x16_bf16(
                    a1, ring[(i - wt) & 3][1], acc[wt], 0, 0, 0);
            // refill slot (i+1)&3 AFTER its last consumers (wt=3 above);
            // no temp double-buffer -> 8 fewer live VGPRs, fits 64-VGPR budget
            if (i < KT - 1) {
                ring[(i + 1) & 3][0] = *reinterpret_cast<const bf16x8*>(Bbase + 64 * (23 - i) + 32);
                ring[(i + 1) & 3][1] = *reinterpret_cast<const bf16x8*>(Bbase + 64 * (23 - i));
            }
        }

        // D: col = lane&31 (t), row f = (r&3) + 8*(r>>2) + 4*g2
#pragma unroll
        for (int wt = 0; wt < 4; ++wt) {
            const int tcol = n0 + 32 * wt + c;
#pragma unroll
            for (int r = 0; r < 16; ++r) {
                const int f = (r & 3) + 8 * (r >> 2) + 4 * g2;
                if (f < NF) outb[f * SEQ + tcol] = acc[wt][r];
            }
        }
    }
}

// ---------------- fallback (verified round-2 kernel, self-staging) ----------------
#define FB_THREADS 512
#define FB_XSTRIDE 5776
#define FB_XN      2864
#define FB_XBYTES  (8 * FB_XSTRIDE)
#define FB_LDSB    (FB_XBYTES + 32 * HSTRIDE_B)   // 97920

__global__ __launch_bounds__(FB_THREADS, 2)
void bpf_mfma_fb(const float* __restrict__ xg, const float* __restrict__ kg,
                 float* __restrict__ out) {
    extern __shared__ char smem[];
    char* xs = smem;
    char* hs = smem + FB_XBYTES;

    const int tid = threadIdx.x;
    const int b   = blockIdx.x >> 2;
    const int T0  = (blockIdx.x & 3) * 2048;
    const int E0  = T0 - 800;

    for (int idx = tid; idx < 32 * 800; idx += FB_THREADS) {
        int f = idx / 800;
        int p = idx - f * 800;
        int k = 791 - p;
        float v = 0.0f;
        if (f < NF && k >= 0 && k < KLEN) v = kg[f * KLEN + k];
        *reinterpret_cast<unsigned short*>(hs + f * HSTRIDE_B + 2 * p) = f2bf(v);
    }
    const float* xb = xg + (size_t)b * SEQ;
    for (int rho = 0; rho < 8; ++rho) {
        char* xr = xs + rho * FB_XSTRIDE;
        for (int e = tid; e < FB_XN; e += FB_THREADS) {
            int g = E0 + rho + e;
            float v = (g >= 0 && g < SEQ) ? xb[g] : 0.0f;
            *reinterpret_cast<unsigned short*>(xr + 2 * e) = f2bf(v);
        }
    }
    __syncthreads();

    const int lane = tid & 63;
    const int wid  = tid >> 6;
    const int c    = lane & 31;
    const int g2   = lane >> 5;
    const char* Abase = hs + c * HSTRIDE_B - 16 * g2;
    float* outb = out + (size_t)b * NF * SEQ;

    for (int ti = 0; ti < 2; ++ti) {
        const int n0     = T0 + (wid + 8 * ti) * 128;
        const int s_base = n0 + c + 1 - 8 * g2 - 784;
        const int rho    = s_base & 7;
        const int ebase  = s_base - rho - E0;
        const char* Bbase = xs + rho * FB_XSTRIDE + 2 * ebase;

        f32x16 acc[4];
#pragma unroll
        for (int wt = 0; wt < 4; ++wt)
#pragma unroll
            for (int r = 0; r < 16; ++r) acc[wt][r] = 0.0f;

        bf16x8 ring[4][2];
#pragma unroll
        for (int wt = 0; wt < 4; ++wt) {
            ring[(4 - wt) & 3][0] = *reinterpret_cast<const bf16x8*>(Bbase + 1568 + 64 * wt);
            ring[(4 - wt) & 3][1] = *reinterpret_cast<const bf16x8*>(Bbase + 1536 + 64 * wt);
        }
#pragma unroll
        for (int i = 0; i < KT; ++i) {
            bf16x8 a0 = *reinterpret_cast<const bf16x8*>(Abase + 1584 - 64 * i);
            bf16x8 a1 = *reinterpret_cast<const bf16x8*>(Abase + 1552 - 64 * i);
#pragma unroll
            for (int wt = 0; wt < 4; ++wt)
                acc[wt] = __builtin_amdgcn_mfma_f32_32x32x16_bf16(
                    a0, ring[(i - wt) & 3][0], acc[wt], 0, 0, 0);
#pragma unroll
            for (int wt = 0; wt < 4; ++wt)
                acc[wt] = __builtin_amdgcn_mfma_f32_32x32x16_bf16(
                    a1, ring[(i - wt) & 3][1], acc[wt], 0, 0, 0);
            if (i < KT - 1) {
                ring[(i + 1) & 3][0] = *reinterpret_cast<const bf16x8*>(Bbase + 64 * (23 - i) + 32);
                ring[(i + 1) & 3][1] = *reinterpret_cast<const bf16x8*>(Bbase + 64 * (23 - i));
            }
        }
#pragma unroll
        for (int wt = 0; wt < 4; ++wt) {
            const int tcol = n0 + 32 * wt + c;
#pragma unroll
            for (int r = 0; r < 16; ++r) {
                const int f = (r & 3) + 8 * (r >> 2) + 4 * g2;
                if (f < NF) outb[f * SEQ + tcol] = acc[wt][r];
            }
        }
    }
}

extern "C" void kernel_launch(void* const* d_in, const int* in_sizes, int n_in,
                              void* d_out, int out_size, void* d_ws, size_t ws_size,
                              hipStream_t stream) {
    const float* x    = (const float*)d_in[0];   // (128,1,8192) f32
    const float* kern = (const float*)d_in[1];   // (20,769)     f32
    float* out = (float*)d_out;                  // (128,1,20,8192) f32
    (void)in_sizes; (void)n_in; (void)out_size;

    if (ws_size >= WS_REQ) {
        char* ws = (char*)d_ws;
        bpf_prep_h<<<32, 256, 0, stream>>>(kern, ws);
        bpf_prep_x<<<dim3(5, BATCH * 8), 256, 0, stream>>>(x, ws + WS_X_OFF);
        hipFuncSetAttribute(reinterpret_cast<const void*>(bpf_mfma_v5),
                            hipFuncAttributeMaxDynamicSharedMemorySize, V5_LDSB);
        bpf_mfma_v5<<<BATCH * 4, V5_THREADS, V5_LDSB, stream>>>(ws + WS_X_OFF, ws, out);
    } else {
        hipFuncSetAttribute(reinterpret_cast<const void*>(bpf_mfma_fb),
                            hipFuncAttributeMaxDynamicSharedMemorySize, FB_LDSB);
        bpf_mfma_fb<<<BATCH * 4, FB_THREADS, FB_LDSB, stream>>>(x, kern, out);
    }
}

// Round 6
// 163.176 us; speedup vs baseline: 1.3189x; 1.2508x over previous
//
#include <hip/hip_runtime.h>
#include <hip/hip_bf16.h>

// out[b,0,f,t] = sum_{k=0}^{768} kernels[f,k] * x[b,0,t-k]  (zero-padded left).
// MFMA Toeplitz-GEMM, v_mfma_f32_32x32x16_bf16, diagonal B-fragment register ring.
// v6 = v5 geometry (78.5 KB LDS -> 2 blocks/CU) + __launch_bounds__(512,2):
// this toolchain treats the 2nd arg as blocks/CU, so 2 -> 128-reg budget
// (round-2-proven no-spill) while LDS now admits 2 blocks = 16 waves/CU.

#define BATCH 128
#define SEQ   8192
#define NF    20
#define KLEN  769
#define KT    25

typedef short bf16x8 __attribute__((ext_vector_type(8)));
typedef float f32x16 __attribute__((ext_vector_type(16)));

static __device__ __forceinline__ unsigned short f2bf(float v) {
    __hip_bfloat16 h = __float2bfloat16(v);
    return *reinterpret_cast<unsigned short*>(&h);
}

// ---------------- workspace layout ----------------
#define HSTRIDE_B 1616      // 808 bf16/row; mod 128 = 80 (conflict-optimal)
#define XROW_B    18016     // 9008 bf16 per (b,rho) row
#define XBSTRIDE_B 144128   // 8 rho-rows per batch
#define WS_X_OFF  65536
#define WS_REQ    (WS_X_OFF + (size_t)BATCH * XBSTRIDE_B)   // ~18.5 MB

// hv[f][p] = kernels[f][791-p] (k-reversed; zero outside [0,769) or f>=20)
__global__ void bpf_prep_h(const float* __restrict__ kg, char* __restrict__ hdst) {
    const int f = blockIdx.x;                 // 0..31
    for (int p = threadIdx.x; p < 808; p += blockDim.x) {
        int k = 791 - p;
        float v = (f < NF && k >= 0 && k < KLEN) ? kg[f * KLEN + k] : 0.0f;
        *reinterpret_cast<unsigned short*>(hdst + f * HSTRIDE_B + 2 * p) = f2bf(v);
    }
}

// xc[b][rho][q] = x[b][q - 800 + rho], q in [0,9008), zero-guarded
__global__ void bpf_prep_x(const float* __restrict__ xg, char* __restrict__ xdst) {
    const int y   = blockIdx.y;               // b*8 + rho
    const int b   = y >> 3;
    const int rho = y & 7;
    const int q0  = (blockIdx.x * blockDim.x + threadIdx.x) * 8;
    if (q0 >= 9008) return;
    const float* xb = xg + (size_t)b * SEQ;
    const int base = q0 - 800 + rho;
    bf16x8 v;
#pragma unroll
    for (int j = 0; j < 8; ++j) {
        int g = base + j;
        float f = (g >= 0 && g < SEQ) ? xb[g] : 0.0f;
        v[j] = (short)f2bf(f);
    }
    *reinterpret_cast<bf16x8*>(xdst + (size_t)y * XROW_B + 2 * q0) = v;
}

// ---------------- main kernel ----------------
#define V6_THREADS 512
#define V6_XS     5776                        // LDS copy stride; mod 128 = 16
#define V6_XREG   (8 * V6_XS)                 // 46208
#define V6_HREG   (NF * HSTRIDE_B)            // 32320 (20 rows only)
#define V6_LDSB   (V6_XREG + V6_HREG)         // 78528 -> 2 blocks/CU

__global__ __launch_bounds__(V6_THREADS, 2)
void bpf_mfma_v6(const char* __restrict__ xsrc_all, const char* __restrict__ hsrc,
                 float* __restrict__ out) {
    extern __shared__ char smem[];
    char* xs = smem;
    char* hs = smem + V6_XREG;

    const int tid = threadIdx.x;
    const int b   = blockIdx.x >> 2;
    const int T0  = (blockIdx.x & 3) * 2048;
    const int E0  = T0 - 800;

    // stage h rows 0..19: contiguous 32320 B = 2020 x 16B (bf16, pre-reversed)
    for (int v = tid; v < 2020; v += V6_THREADS) {
        *reinterpret_cast<bf16x8*>(hs + v * 16) =
            *reinterpret_cast<const bf16x8*>(hsrc + v * 16);
    }
    // stage x: 8 copies x 5712 B (357 x 16B each) from pre-shifted WS rows
    {
        const char* xsrcb = xsrc_all + (size_t)b * XBSTRIDE_B + 2 * T0;
        for (int v = tid; v < 8 * 357; v += V6_THREADS) {
            int rho = v / 357;
            int j   = v - rho * 357;
            *reinterpret_cast<bf16x8*>(xs + rho * V6_XS + j * 16) =
                *reinterpret_cast<const bf16x8*>(xsrcb + rho * XROW_B + j * 16);
        }
    }
    __syncthreads();

    const int lane = tid & 63;
    const int wid  = tid >> 6;    // 0..7
    const int c    = lane & 31;   // A row (=f), B col (=t-offset), D col
    const int g2   = lane >> 5;

    // lanes c>=20 read h row 0 (their D rows are discarded; A row m only feeds D row m)
    const int hrow = (c < NF) ? c : 0;
    const char* Abase = hs + hrow * HSTRIDE_B - 16 * g2;
    float* outb = out + (size_t)b * NF * SEQ;

    for (int ti = 0; ti < 2; ++ti) {
        const int n0     = T0 + (wid + 8 * ti) * 128;   // 128 t-cols per task
        const int s_base = n0 + c + 1 - 8 * g2 - 784;
        const int rho    = s_base & 7;
        const int ebase  = s_base - rho - E0;           // >= 2, == 0 mod 8
        const char* Bbase = xs + rho * V6_XS + 2 * ebase;

        f32x16 acc[4];
#pragma unroll
        for (int wt = 0; wt < 4; ++wt)
#pragma unroll
            for (int r = 0; r < 16; ++r) acc[wt][r] = 0.0f;

        // prologue: pair(0,wt) -> ring[(4-wt)&3]
        bf16x8 ring[4][2];
#pragma unroll
        for (int wt = 0; wt < 4; ++wt) {
            ring[(4 - wt) & 3][0] = *reinterpret_cast<const bf16x8*>(Bbase + 1568 + 64 * wt);
            ring[(4 - wt) & 3][1] = *reinterpret_cast<const bf16x8*>(Bbase + 1536 + 64 * wt);
        }

#pragma unroll
        for (int i = 0; i < KT; ++i) {
            bf16x8 a0 = *reinterpret_cast<const bf16x8*>(Abase + 1584 - 64 * i);
            bf16x8 a1 = *reinterpret_cast<const bf16x8*>(Abase + 1552 - 64 * i);
#pragma unroll
            for (int wt = 0; wt < 4; ++wt)
                acc[wt] = __builtin_amdgcn_mfma_f32_32x32x16_bf16(
                    a0, ring[(i - wt) & 3][0], acc[wt], 0, 0, 0);
#pragma unroll
            for (int wt = 0; wt < 4; ++wt)
                acc[wt] = __builtin_amdgcn_mfma_f32_32x32x16_bf16(
                    a1, ring[(i - wt) & 3][1], acc[wt], 0, 0, 0);
            // refill slot (i+1)&3 AFTER its last consumers (wt=3 above)
            if (i < KT - 1) {
                ring[(i + 1) & 3][0] = *reinterpret_cast<const bf16x8*>(Bbase + 64 * (23 - i) + 32);
                ring[(i + 1) & 3][1] = *reinterpret_cast<const bf16x8*>(Bbase + 64 * (23 - i));
            }
        }

        // D: col = lane&31 (t), row f = (r&3) + 8*(r>>2) + 4*g2
#pragma unroll
        for (int wt = 0; wt < 4; ++wt) {
            const int tcol = n0 + 32 * wt + c;
#pragma unroll
            for (int r = 0; r < 16; ++r) {
                const int f = (r & 3) + 8 * (r >> 2) + 4 * g2;
                if (f < NF) outb[f * SEQ + tcol] = acc[wt][r];
            }
        }
    }
}

// ---------------- fallback (verified round-2 kernel, self-staging) ----------------
#define FB_THREADS 512
#define FB_XSTRIDE 5776
#define FB_XN      2864
#define FB_XBYTES  (8 * FB_XSTRIDE)
#define FB_LDSB    (FB_XBYTES + 32 * HSTRIDE_B)   // 97920

__global__ __launch_bounds__(FB_THREADS, 2)
void bpf_mfma_fb(const float* __restrict__ xg, const float* __restrict__ kg,
                 float* __restrict__ out) {
    extern __shared__ char smem[];
    char* xs = smem;
    char* hs = smem + FB_XBYTES;

    const int tid = threadIdx.x;
    const int b   = blockIdx.x >> 2;
    const int T0  = (blockIdx.x & 3) * 2048;
    const int E0  = T0 - 800;

    for (int idx = tid; idx < 32 * 800; idx += FB_THREADS) {
        int f = idx / 800;
        int p = idx - f * 800;
        int k = 791 - p;
        float v = 0.0f;
        if (f < NF && k >= 0 && k < KLEN) v = kg[f * KLEN + k];
        *reinterpret_cast<unsigned short*>(hs + f * HSTRIDE_B + 2 * p) = f2bf(v);
    }
    const float* xb = xg + (size_t)b * SEQ;
    for (int rho = 0; rho < 8; ++rho) {
        char* xr = xs + rho * FB_XSTRIDE;
        for (int e = tid; e < FB_XN; e += FB_THREADS) {
            int g = E0 + rho + e;
            float v = (g >= 0 && g < SEQ) ? xb[g] : 0.0f;
            *reinterpret_cast<unsigned short*>(xr + 2 * e) = f2bf(v);
        }
    }
    __syncthreads();

    const int lane = tid & 63;
    const int wid  = tid >> 6;
    const int c    = lane & 31;
    const int g2   = lane >> 5;
    const char* Abase = hs + c * HSTRIDE_B - 16 * g2;
    float* outb = out + (size_t)b * NF * SEQ;

    for (int ti = 0; ti < 2; ++ti) {
        const int n0     = T0 + (wid + 8 * ti) * 128;
        const int s_base = n0 + c + 1 - 8 * g2 - 784;
        const int rho    = s_base & 7;
        const int ebase  = s_base - rho - E0;
        const char* Bbase = xs + rho * FB_XSTRIDE + 2 * ebase;

        f32x16 acc[4];
#pragma unroll
        for (int wt = 0; wt < 4; ++wt)
#pragma unroll
            for (int r = 0; r < 16; ++r) acc[wt][r] = 0.0f;

        bf16x8 ring[4][2];
#pragma unroll
        for (int wt = 0; wt < 4; ++wt) {
            ring[(4 - wt) & 3][0] = *reinterpret_cast<const bf16x8*>(Bbase + 1568 + 64 * wt);
            ring[(4 - wt) & 3][1] = *reinterpret_cast<const bf16x8*>(Bbase + 1536 + 64 * wt);
        }
#pragma unroll
        for (int i = 0; i < KT; ++i) {
            bf16x8 a0 = *reinterpret_cast<const bf16x8*>(Abase + 1584 - 64 * i);
            bf16x8 a1 = *reinterpret_cast<const bf16x8*>(Abase + 1552 - 64 * i);
#pragma unroll
            for (int wt = 0; wt < 4; ++wt)
                acc[wt] = __builtin_amdgcn_mfma_f32_32x32x16_bf16(
                    a0, ring[(i - wt) & 3][0], acc[wt], 0, 0, 0);
#pragma unroll
            for (int wt = 0; wt < 4; ++wt)
                acc[wt] = __builtin_amdgcn_mfma_f32_32x32x16_bf16(
                    a1, ring[(i - wt) & 3][1], acc[wt], 0, 0, 0);
            if (i < KT - 1) {
                ring[(i + 1) & 3][0] = *reinterpret_cast<const bf16x8*>(Bbase + 64 * (23 - i) + 32);
                ring[(i + 1) & 3][1] = *reinterpret_cast<const bf16x8*>(Bbase + 64 * (23 - i));
            }
        }
#pragma unroll
        for (int wt = 0; wt < 4; ++wt) {
            const int tcol = n0 + 32 * wt + c;
#pragma unroll
            for (int r = 0; r < 16; ++r) {
                const int f = (r & 3) + 8 * (r >> 2) + 4 * g2;
                if (f < NF) outb[f * SEQ + tcol] = acc[wt][r];
            }
        }
    }
}

extern "C" void kernel_launch(void* const* d_in, const int* in_sizes, int n_in,
                              void* d_out, int out_size, void* d_ws, size_t ws_size,
                              hipStream_t stream) {
    const float* x    = (const float*)d_in[0];   // (128,1,8192) f32
    const float* kern = (const float*)d_in[1];   // (20,769)     f32
    float* out = (float*)d_out;                  // (128,1,20,8192) f32
    (void)in_sizes; (void)n_in; (void)out_size;

    if (ws_size >= WS_REQ) {
        char* ws = (char*)d_ws;
        bpf_prep_h<<<32, 256, 0, stream>>>(kern, ws);
        bpf_prep_x<<<dim3(5, BATCH * 8), 256, 0, stream>>>(x, ws + WS_X_OFF);
        hipFuncSetAttribute(reinterpret_cast<const void*>(bpf_mfma_v6),
                            hipFuncAttributeMaxDynamicSharedMemorySize, V6_LDSB);
        bpf_mfma_v6<<<BATCH * 4, V6_THREADS, V6_LDSB, stream>>>(ws + WS_X_OFF, ws, out);
    } else {
        hipFuncSetAttribute(reinterpret_cast<const void*>(bpf_mfma_fb),
                            hipFuncAttributeMaxDynamicSharedMemorySize, FB_LDSB);
        bpf_mfma_fb<<<BATCH * 4, FB_THREADS, FB_LDSB, stream>>>(x, kern, out);
    }
}

// Round 7
// 151.131 us; speedup vs baseline: 1.4240x; 1.0797x over previous
//
#include <hip/hip_runtime.h>
#include <hip/hip_bf16.h>

// out[b,0,f,t] = sum_{k=0}^{768} kernels[f,k] * x[b,0,t-k]  (zero-padded left).
// MFMA Toeplitz-GEMM, v_mfma_f32_32x32x16_bf16, diagonal B-fragment register ring.
// v7 = v6 geometry (78.5 KB LDS -> 2 blocks/CU, __launch_bounds__(512,2) ->
// 128-reg no-spill budget) + round-2-proven ring schedule: prefetch next ring
// pair into temps at TOP of iter (8 MFMAs of latency cover), move into ring
// after last consumer. v6's in-loop refill exposed ~full LDS latency per iter
// because slot (i+1)&3 is the FIRST operand of iter i+1.

#define BATCH 128
#define SEQ   8192
#define NF    20
#define KLEN  769
#define KT    25

typedef short bf16x8 __attribute__((ext_vector_type(8)));
typedef float f32x16 __attribute__((ext_vector_type(16)));

static __device__ __forceinline__ unsigned short f2bf(float v) {
    __hip_bfloat16 h = __float2bfloat16(v);
    return *reinterpret_cast<unsigned short*>(&h);
}

// ---------------- workspace layout ----------------
#define HSTRIDE_B 1616      // 808 bf16/row; mod 128 = 80 (conflict-optimal)
#define XROW_B    18016     // 9008 bf16 per (b,rho) row
#define XBSTRIDE_B 144128   // 8 rho-rows per batch
#define WS_X_OFF  65536
#define WS_REQ    (WS_X_OFF + (size_t)BATCH * XBSTRIDE_B)   // ~18.5 MB

// Fused prep: blocks 0..31 -> h rows (k-reversed, zero-padded);
// blocks 32.. -> x shifted copies xc[b][rho][q] = x[b][q - 800 + rho].
__global__ void bpf_prep(const float* __restrict__ kg, const float* __restrict__ xg,
                         char* __restrict__ ws) {
    const int bid = blockIdx.x;
    const int tid = threadIdx.x;
    if (bid < 32) {
        const int f = bid;
        char* hdst = ws;
        for (int p = tid; p < 808; p += 256) {
            int k = 791 - p;
            float v = (f < NF && k >= 0 && k < KLEN) ? kg[f * KLEN + k] : 0.0f;
            *reinterpret_cast<unsigned short*>(hdst + f * HSTRIDE_B + 2 * p) = f2bf(v);
        }
    } else {
        const int id2 = bid - 32;
        const int y    = id2 / 5;           // b*8 + rho, 0..1023
        const int part = id2 - y * 5;
        const int b    = y >> 3;
        const int rho  = y & 7;
        const int q0   = (part * 256 + tid) * 8;
        if (q0 >= 9008) return;
        const float* xb = xg + (size_t)b * SEQ;
        const int base = q0 - 800 + rho;
        bf16x8 v;
#pragma unroll
        for (int j = 0; j < 8; ++j) {
            int g = base + j;
            float f = (g >= 0 && g < SEQ) ? xb[g] : 0.0f;
            v[j] = (short)f2bf(f);
        }
        *reinterpret_cast<bf16x8*>(ws + WS_X_OFF + (size_t)y * XROW_B + 2 * q0) = v;
    }
}

// ---------------- main kernel ----------------
#define V7_THREADS 512
#define V7_XS     5776                        // LDS copy stride; mod 128 = 16
#define V7_XREG   (8 * V7_XS)                 // 46208
#define V7_HREG   (NF * HSTRIDE_B)            // 32320 (20 rows only)
#define V7_LDSB   (V7_XREG + V7_HREG)         // 78528 -> 2 blocks/CU

__global__ __launch_bounds__(V7_THREADS, 2)
void bpf_mfma_v7(const char* __restrict__ xsrc_all, const char* __restrict__ hsrc,
                 float* __restrict__ out) {
    extern __shared__ char smem[];
    char* xs = smem;
    char* hs = smem + V7_XREG;

    const int tid = threadIdx.x;
    const int b   = blockIdx.x >> 2;
    const int T0  = (blockIdx.x & 3) * 2048;
    const int E0  = T0 - 800;

    // stage h rows 0..19: contiguous 32320 B = 2020 x 16B (bf16, pre-reversed)
    for (int v = tid; v < 2020; v += V7_THREADS) {
        *reinterpret_cast<bf16x8*>(hs + v * 16) =
            *reinterpret_cast<const bf16x8*>(hsrc + v * 16);
    }
    // stage x: 8 copies x 5712 B (357 x 16B each) from pre-shifted WS rows
    {
        const char* xsrcb = xsrc_all + (size_t)b * XBSTRIDE_B + 2 * T0;
        for (int v = tid; v < 8 * 357; v += V7_THREADS) {
            int rho = v / 357;
            int j   = v - rho * 357;
            *reinterpret_cast<bf16x8*>(xs + rho * V7_XS + j * 16) =
                *reinterpret_cast<const bf16x8*>(xsrcb + rho * XROW_B + j * 16);
        }
    }
    __syncthreads();

    const int lane = tid & 63;
    const int wid  = tid >> 6;    // 0..7
    const int c    = lane & 31;   // A row (=f), B col (=t-offset), D col
    const int g2   = lane >> 5;

    // lanes c>=20 read h row 0 (their D rows are discarded; A row m only feeds D row m)
    const int hrow = (c < NF) ? c : 0;
    const char* Abase = hs + hrow * HSTRIDE_B - 16 * g2;
    float* outb = out + (size_t)b * NF * SEQ;

    for (int ti = 0; ti < 2; ++ti) {
        const int n0     = T0 + (wid + 8 * ti) * 128;   // 128 t-cols per task
        const int s_base = n0 + c + 1 - 8 * g2 - 784;
        const int rho    = s_base & 7;
        const int ebase  = s_base - rho - E0;           // >= 2, == 0 mod 8
        const char* Bbase = xs + rho * V7_XS + 2 * ebase;

        f32x16 acc[4];
#pragma unroll
        for (int wt = 0; wt < 4; ++wt)
#pragma unroll
            for (int r = 0; r < 16; ++r) acc[wt][r] = 0.0f;

        // prologue: pair(0,wt) -> ring[(4-wt)&3]
        bf16x8 ring[4][2];
#pragma unroll
        for (int wt = 0; wt < 4; ++wt) {
            ring[(4 - wt) & 3][0] = *reinterpret_cast<const bf16x8*>(Bbase + 1568 + 64 * wt);
            ring[(4 - wt) & 3][1] = *reinterpret_cast<const bf16x8*>(Bbase + 1536 + 64 * wt);
        }

#pragma unroll
        for (int i = 0; i < KT; ++i) {
            // prefetch pair(i+1, 0) into temps at TOP: 8 MFMAs of latency cover
            bf16x8 na, nb;
            if (i < KT - 1) {
                na = *reinterpret_cast<const bf16x8*>(Bbase + 64 * (23 - i) + 32);
                nb = *reinterpret_cast<const bf16x8*>(Bbase + 64 * (23 - i));
            }
            bf16x8 a0 = *reinterpret_cast<const bf16x8*>(Abase + 1584 - 64 * i);
            bf16x8 a1 = *reinterpret_cast<const bf16x8*>(Abase + 1552 - 64 * i);
#pragma unroll
            for (int wt = 0; wt < 4; ++wt)
                acc[wt] = __builtin_amdgcn_mfma_f32_32x32x16_bf16(
                    a0, ring[(i - wt) & 3][0], acc[wt], 0, 0, 0);
#pragma unroll
            for (int wt = 0; wt < 4; ++wt)
                acc[wt] = __builtin_amdgcn_mfma_f32_32x32x16_bf16(
                    a1, ring[(i - wt) & 3][1], acc[wt], 0, 0, 0);
            // move temps into ring AFTER its last consumer (wt=3 above)
            if (i < KT - 1) {
                ring[(i + 1) & 3][0] = na;
                ring[(i + 1) & 3][1] = nb;
            }
        }

        // D: col = lane&31 (t), row f = (r&3) + 8*(r>>2) + 4*g2
#pragma unroll
        for (int wt = 0; wt < 4; ++wt) {
            const int tcol = n0 + 32 * wt + c;
#pragma unroll
            for (int r = 0; r < 16; ++r) {
                const int f = (r & 3) + 8 * (r >> 2) + 4 * g2;
                if (f < NF) outb[f * SEQ + tcol] = acc[wt][r];
            }
        }
    }
}

// ---------------- fallback (verified round-2 kernel, self-staging) ----------------
#define FB_THREADS 512
#define FB_XSTRIDE 5776
#define FB_XN      2864
#define FB_XBYTES  (8 * FB_XSTRIDE)
#define FB_LDSB    (FB_XBYTES + 32 * HSTRIDE_B)   // 97920

__global__ __launch_bounds__(FB_THREADS, 2)
void bpf_mfma_fb(const float* __restrict__ xg, const float* __restrict__ kg,
                 float* __restrict__ out) {
    extern __shared__ char smem[];
    char* xs = smem;
    char* hs = smem + FB_XBYTES;

    const int tid = threadIdx.x;
    const int b   = blockIdx.x >> 2;
    const int T0  = (blockIdx.x & 3) * 2048;
    const int E0  = T0 - 800;

    for (int idx = tid; idx < 32 * 800; idx += FB_THREADS) {
        int f = idx / 800;
        int p = idx - f * 800;
        int k = 791 - p;
        float v = 0.0f;
        if (f < NF && k >= 0 && k < KLEN) v = kg[f * KLEN + k];
        *reinterpret_cast<unsigned short*>(hs + f * HSTRIDE_B + 2 * p) = f2bf(v);
    }
    const float* xb = xg + (size_t)b * SEQ;
    for (int rho = 0; rho < 8; ++rho) {
        char* xr = xs + rho * FB_XSTRIDE;
        for (int e = tid; e < FB_XN; e += FB_THREADS) {
            int g = E0 + rho + e;
            float v = (g >= 0 && g < SEQ) ? xb[g] : 0.0f;
            *reinterpret_cast<unsigned short*>(xr + 2 * e) = f2bf(v);
        }
    }
    __syncthreads();

    const int lane = tid & 63;
    const int wid  = tid >> 6;
    const int c    = lane & 31;
    const int g2   = lane >> 5;
    const char* Abase = hs + c * HSTRIDE_B - 16 * g2;
    float* outb = out + (size_t)b * NF * SEQ;

    for (int ti = 0; ti < 2; ++ti) {
        const int n0     = T0 + (wid + 8 * ti) * 128;
        const int s_base = n0 + c + 1 - 8 * g2 - 784;
        const int rho    = s_base & 7;
        const int ebase  = s_base - rho - E0;
        const char* Bbase = xs + rho * FB_XSTRIDE + 2 * ebase;

        f32x16 acc[4];
#pragma unroll
        for (int wt = 0; wt < 4; ++wt)
#pragma unroll
            for (int r = 0; r < 16; ++r) acc[wt][r] = 0.0f;

        bf16x8 ring[4][2];
#pragma unroll
        for (int wt = 0; wt < 4; ++wt) {
            ring[(4 - wt) & 3][0] = *reinterpret_cast<const bf16x8*>(Bbase + 1568 + 64 * wt);
            ring[(4 - wt) & 3][1] = *reinterpret_cast<const bf16x8*>(Bbase + 1536 + 64 * wt);
        }
#pragma unroll
        for (int i = 0; i < KT; ++i) {
            bf16x8 na, nb;
            if (i < KT - 1) {
                na = *reinterpret_cast<const bf16x8*>(Bbase + 64 * (23 - i) + 32);
                nb = *reinterpret_cast<const bf16x8*>(Bbase + 64 * (23 - i));
            }
            bf16x8 a0 = *reinterpret_cast<const bf16x8*>(Abase + 1584 - 64 * i);
            bf16x8 a1 = *reinterpret_cast<const bf16x8*>(Abase + 1552 - 64 * i);
#pragma unroll
            for (int wt = 0; wt < 4; ++wt)
                acc[wt] = __builtin_amdgcn_mfma_f32_32x32x16_bf16(
                    a0, ring[(i - wt) & 3][0], acc[wt], 0, 0, 0);
#pragma unroll
            for (int wt = 0; wt < 4; ++wt)
                acc[wt] = __builtin_amdgcn_mfma_f32_32x32x16_bf16(
                    a1, ring[(i - wt) & 3][1], acc[wt], 0, 0, 0);
            if (i < KT - 1) {
                ring[(i + 1) & 3][0] = na;
                ring[(i + 1) & 3][1] = nb;
            }
        }
#pragma unroll
        for (int wt = 0; wt < 4; ++wt) {
            const int tcol = n0 + 32 * wt + c;
#pragma unroll
            for (int r = 0; r < 16; ++r) {
                const int f = (r & 3) + 8 * (r >> 2) + 4 * g2;
                if (f < NF) outb[f * SEQ + tcol] = acc[wt][r];
            }
        }
    }
}

extern "C" void kernel_launch(void* const* d_in, const int* in_sizes, int n_in,
                              void* d_out, int out_size, void* d_ws, size_t ws_size,
                              hipStream_t stream) {
    const float* x    = (const float*)d_in[0];   // (128,1,8192) f32
    const float* kern = (const float*)d_in[1];   // (20,769)     f32
    float* out = (float*)d_out;                  // (128,1,20,8192) f32
    (void)in_sizes; (void)n_in; (void)out_size;

    if (ws_size >= WS_REQ) {
        char* ws = (char*)d_ws;
        bpf_prep<<<32 + 5 * BATCH * 8, 256, 0, stream>>>(kern, x, ws);
        hipFuncSetAttribute(reinterpret_cast<const void*>(bpf_mfma_v7),
                            hipFuncAttributeMaxDynamicSharedMemorySize, V7_LDSB);
        bpf_mfma_v7<<<BATCH * 4, V7_THREADS, V7_LDSB, stream>>>(ws + WS_X_OFF, ws, out);
    } else {
        hipFuncSetAttribute(reinterpret_cast<const void*>(bpf_mfma_fb),
                            hipFuncAttributeMaxDynamicSharedMemorySize, FB_LDSB);
        bpf_mfma_fb<<<BATCH * 4, FB_THREADS, FB_LDSB, stream>>>(x, kern, out);
    }
}